// Round 10
// baseline (164.286 us; speedup 1.0000x reference)
//
#include <hip/hip_runtime.h>
#include <hip/hip_bf16.h>

#define N_NODES 20000
#define BATCH   4
#define F_DIM   256
#define O_DIM   256
#define E_EDGES 160000
#define M_ROWS  (BATCH * N_NODES)   // 80000
#define K_DIM   512                 // concat: X (slices 0-7) | Xagg (slices 8-15)
// A layout: [16 slices][80000 rows][32 feats] bf16; row m = n*4 + b.
#define SLICE_A   2560000          // elems per A slice (80000*32)
#define SLICE_W   8192             // elems per Wt slice (256*32)

typedef __bf16 bf16_t;
typedef bf16_t bf16x8 __attribute__((ext_vector_type(8)));
typedef float  f32x4  __attribute__((ext_vector_type(4)));

// ---------- K1: fused X->bf16 sliced convert + weight transpose + deg zero ----------
__global__ void __launch_bounds__(256) k_prep(const float* __restrict__ X,
                                              const float* __restrict__ W1,
                                              const float* __restrict__ W2,
                                              bf16_t* __restrict__ A,
                                              bf16_t* __restrict__ Wt,
                                              int* __restrict__ deg) {
    const int bid = blockIdx.x;
    const int tid = threadIdx.x;
    if (bid < 10000) {
        const int m = bid * 8 + (tid >> 5);      // m = n*4 + b
        const int n = m >> 2, b = m & 3;
        const int col = (tid & 31) * 8;          // feat octet
        const float* src = X + ((size_t)b * N_NODES + n) * F_DIM + col;
        const float4 v0 = *reinterpret_cast<const float4*>(src);
        const float4 v1 = *reinterpret_cast<const float4*>(src + 4);
        bf16x8 o = { (bf16_t)v0.x, (bf16_t)v0.y, (bf16_t)v0.z, (bf16_t)v0.w,
                     (bf16_t)v1.x, (bf16_t)v1.y, (bf16_t)v1.z, (bf16_t)v1.w };
        const int s = col >> 5;
        *reinterpret_cast<bf16x8*>(A + (size_t)s * SLICE_A + (size_t)m * 32 + (col & 31)) = o;
    } else if (bid < 10512) {
        const int k = bid - 10000;   // 0..511
        const float v = (k < F_DIM) ? W1[(size_t)k * O_DIM + tid]
                                    : W2[(size_t)(k - F_DIM) * O_DIM + tid];
        Wt[(size_t)(k >> 5) * SLICE_W + (size_t)tid * 32 + (k & 31)] = (bf16_t)v;
    } else {
        const int idx = (bid - 10512) * 256 + tid;
        if (idx < N_NODES) deg[idx] = 0;
    }
}

// ---------- CSR build ----------
__global__ void k_deg(const int* __restrict__ rows, int* __restrict__ deg) {
    int e = blockIdx.x * 256 + threadIdx.x;
    atomicAdd(&deg[rows[e]], 1);
}

__global__ void __launch_bounds__(1024) k_scan(const int* __restrict__ deg,
                                               int* __restrict__ offsets,
                                               int* __restrict__ cursor) {
    __shared__ int wsum[16];
    const int t = threadIdx.x;          // 0..1023
    const int lane = t & 63, wv = t >> 6;
    const int CH = 20;
    int b = t * CH; if (b > N_NODES) b = N_NODES;
    int e = b + CH; if (e > N_NODES) e = N_NODES;
    int s = 0;
    for (int i = b; i < e; ++i) s += deg[i];
    int ps = s;
#pragma unroll
    for (int off = 1; off < 64; off <<= 1) {
        int o = __shfl_up(ps, off);
        if (lane >= off) ps += o;
    }
    if (lane == 63) wsum[wv] = ps;
    __syncthreads();
    if (t == 0) {
        int run = 0;
#pragma unroll
        for (int j = 0; j < 16; ++j) { int v = wsum[j]; wsum[j] = run; run += v; }
        offsets[N_NODES] = run;         // == E
    }
    __syncthreads();
    int run = wsum[wv] + (ps - s);
    for (int i = b; i < e; ++i) {
        offsets[i] = run; cursor[i] = run;
        run += deg[i];
    }
}

__global__ void k_scatter(const int* __restrict__ rows, const int* __restrict__ cols,
                          const float* __restrict__ vals, int* __restrict__ cursor,
                          int* __restrict__ ccol, float* __restrict__ cval) {
    int e = blockIdx.x * 256 + threadIdx.x;
    int r = rows[e];
    int p = atomicAdd(&cursor[r], 1);
    ccol[p] = cols[e];
    cval[p] = vals[e];
}

// ---------- SpMM: sliced + XCD-pinned, WAVE-per-node (uniform trip count) ----------
// r8's group-per-node made 4 groups of one wave walk different nodes ->
// per-wave iterations = max(deg of 4 nodes) ~ 12 vs mean 8 (40% masked waste).
// Now: wave = node (loop bound wave-uniform), groups g=0..3 stride the edge
// list by 4, unroll-2 (8 gathers in flight/wave), ONE end-join (2 shfl_xor).
__global__ void __launch_bounds__(256) k_spmm(const bf16_t* __restrict__ A,
                                              const int* __restrict__ offsets,
                                              const int* __restrict__ ccol,
                                              const float* __restrict__ cval,
                                              bf16_t* __restrict__ Aout) {
    const int x = blockIdx.x & 7;                  // slice / XCD pin
    const int chunk = blockIdx.x >> 3;             // 0..4999
    const int wv = threadIdx.x >> 6;               // 0..3: node within block
    const int lane = threadIdx.x & 63;
    const int g = lane >> 4, sub = lane & 15;      // group, (batch|feat-octet)
    const int n = chunk * 4 + wv;
    const bf16_t* Xs = A + (size_t)x * SLICE_A + sub * 8;
    const int beg = offsets[n], end = offsets[n + 1];
    float acc[8] = {0.f,0.f,0.f,0.f,0.f,0.f,0.f,0.f};
    int i = beg + g;
    for (; i + 4 < end; i += 8) {                  // pair (i, i+4) both valid
        const int   c0 = ccol[i],   c1 = ccol[i + 4];
        const float v0 = cval[i],   v1 = cval[i + 4];
        bf16x8 x0 = *reinterpret_cast<const bf16x8*>(Xs + (size_t)c0 * 128);
        bf16x8 x1 = *reinterpret_cast<const bf16x8*>(Xs + (size_t)c1 * 128);
#pragma unroll
        for (int j = 0; j < 8; ++j)
            acc[j] += v0 * (float)x0[j] + v1 * (float)x1[j];
    }
    if (i < end) {
        const int c0 = ccol[i];
        const float v0 = cval[i];
        bf16x8 x0 = *reinterpret_cast<const bf16x8*>(Xs + (size_t)c0 * 128);
#pragma unroll
        for (int j = 0; j < 8; ++j) acc[j] += v0 * (float)x0[j];
    }
#pragma unroll
    for (int j = 0; j < 8; ++j) {                  // single end-join across groups
        acc[j] += __shfl_xor(acc[j], 16);
        acc[j] += __shfl_xor(acc[j], 32);
    }
    if (g == 0) {
        bf16x8 o = { (bf16_t)acc[0], (bf16_t)acc[1], (bf16_t)acc[2], (bf16_t)acc[3],
                     (bf16_t)acc[4], (bf16_t)acc[5], (bf16_t)acc[6], (bf16_t)acc[7] };
        *reinterpret_cast<bf16x8*>(
            Aout + (size_t)(8 + x) * SLICE_A + (size_t)n * 128 + sub * 8) = o;
    }
}

// ---------- GEMM (r8 version, best measured): BK=64, 64KB LDS dbuf, src-side
// XOR swizzle chunk^=row&7, bijective XCD pairing of the two n-tiles ----------
#define GLOAD_LDS16(gptr, lptr)                                                  \
    __builtin_amdgcn_global_load_lds(                                            \
        (const __attribute__((address_space(1))) unsigned int*)(gptr),           \
        (__attribute__((address_space(3))) unsigned int*)(lptr), 16, 0, 0)

__global__ void __launch_bounds__(256, 2) k_gemm(const bf16_t* __restrict__ A,   // sliced
                                                 const bf16_t* __restrict__ Bt,  // sliced Wt
                                                 const float* __restrict__ bias,
                                                 float* __restrict__ out) {      // [B*N][256]
    __shared__ bf16_t As[2 * 128 * 64];   // 32 KB
    __shared__ bf16_t Bs[2 * 128 * 64];   // 32 KB

    const int b0 = blockIdx.x;
    const int xcd = b0 & 7, idx = b0 >> 3;
    const int serial = (xcd < 2 ? xcd * 157 : 314 + (xcd - 2) * 156) + idx;
    const int tile_m = (serial >> 1) * 128;
    const int tile_n = (serial & 1) * 128;

    const int tid = threadIdx.x;
    const int lane = tid & 63;
    const int w = tid >> 6;
    const int wm = (w >> 1) * 64;
    const int wn = (w & 1) * 64;

    f32x4 acc[4][4];
#pragma unroll
    for (int i = 0; i < 4; ++i)
#pragma unroll
        for (int j = 0; j < 4; ++j) acc[i][j] = (f32x4){0.f, 0.f, 0.f, 0.f};

    // K-step t covers slices {2t, 2t+1}. LDS[row][j] = source chunk jj = j^(row&7);
    // chunk jj -> slice 2t+(jj>>2), in-slice offset row*32 + (jj&3)*8.
    auto STAGE = [&](int buf, int t) {
#pragma unroll
        for (int r = 0; r < 4; ++r) {
            const int c = r * 256 + tid;           // 0..1023
            const int row = c >> 3;
            const int jj = (c & 7) ^ (row & 7);
            const int s = t * 2 + (jj >> 2);
            GLOAD_LDS16(A  + (size_t)s * SLICE_A + (size_t)(tile_m + row) * 32 + (jj & 3) * 8,
                        &As[buf * 8192 + c * 8]);
            GLOAD_LDS16(Bt + (size_t)s * SLICE_W + (size_t)(tile_n + row) * 32 + (jj & 3) * 8,
                        &Bs[buf * 8192 + c * 8]);
        }
    };
    auto COMPUTE = [&](int buf) {
        const bf16_t* a  = &As[buf * 8192];
        const bf16_t* bb = &Bs[buf * 8192];
#pragma unroll
        for (int ks = 0; ks < 2; ++ks) {
            const int ch = ((((ks << 2) | (lane >> 4)) ^ (lane & 7)) << 3);
            bf16x8 af[4];
#pragma unroll
            for (int i = 0; i < 4; ++i)
                af[i] = *reinterpret_cast<const bf16x8*>(a + (wm + i * 16 + (lane & 15)) * 64 + ch);
#pragma unroll
            for (int j = 0; j < 4; ++j) {
                bf16x8 bfr = *reinterpret_cast<const bf16x8*>(bb + (wn + j * 16 + (lane & 15)) * 64 + ch);
#pragma unroll
                for (int i = 0; i < 4; ++i)
                    acc[i][j] = __builtin_amdgcn_mfma_f32_16x16x32_bf16(af[i], bfr, acc[i][j], 0, 0, 0);
            }
        }
    };

    STAGE(0, 0);
    __syncthreads();
#pragma unroll
    for (int t = 0; t < 8; t += 2) {
        STAGE(1, t + 1);
        COMPUTE(0);
        __syncthreads();
        if (t + 2 < 8) STAGE(0, t + 2);
        COMPUTE(1);
        __syncthreads();
    }

#pragma unroll
    for (int j = 0; j < 4; ++j) {
        const int col = tile_n + wn + j * 16 + (lane & 15);
        const float bv = bias[col];
#pragma unroll
        for (int i = 0; i < 4; ++i) {
            const int m0 = tile_m + wm + i * 16 + ((lane >> 4) << 2);
#pragma unroll
            for (int r = 0; r < 4; ++r) {
                const int m = m0 + r;                       // m = n*4 + b
                const size_t orow = (size_t)(m & 3) * N_NODES + (m >> 2);
                out[orow * O_DIM + col] = acc[i][j][r] + bv;
            }
        }
    }
}

extern "C" void kernel_launch(void* const* d_in, const int* in_sizes, int n_in,
                              void* d_out, int out_size, void* d_ws, size_t ws_size,
                              hipStream_t stream) {
    const float* X    = (const float*)d_in[0];
    const int*   rows = (const int*)d_in[1];
    const int*   cols = (const int*)d_in[2];
    const float* vals = (const float*)d_in[3];
    const float* W1   = (const float*)d_in[4];
    const float* W2   = (const float*)d_in[5];
    const float* bias = (const float*)d_in[6];
    float* out = (float*)d_out;

    char* ws = (char*)d_ws;
    size_t off = 0;
    bf16_t* Abuf = (bf16_t*)(ws + off); off += (size_t)16 * SLICE_A * 2;     // 81,920,000 B
    bf16_t* Wt   = (bf16_t*)(ws + off); off += (size_t)16 * SLICE_W * 2;     // 262,144 B
    int* deg     = (int*)(ws + off);    off += (size_t)N_NODES * 4;
    int* offsets = (int*)(ws + off);    off += (size_t)(N_NODES + 1) * 4;
    int* cursor  = (int*)(ws + off);    off += (size_t)N_NODES * 4;
    off = (off + 15) & ~(size_t)15;
    int*   ccol  = (int*)(ws + off);    off += (size_t)E_EDGES * 4;
    float* cval  = (float*)(ws + off);  off += (size_t)E_EDGES * 4;

    k_prep<<<10591, 256, 0, stream>>>(X, W1, W2, Abuf, Wt, deg);
    k_deg<<<E_EDGES / 256, 256, 0, stream>>>(rows, deg);
    k_scan<<<1, 1024, 0, stream>>>(deg, offsets, cursor);
    k_scatter<<<E_EDGES / 256, 256, 0, stream>>>(rows, cols, vals, cursor, ccol, cval);
    k_spmm<<<40000, 256, 0, stream>>>(Abuf, offsets, ccol, cval, Abuf);
    k_gemm<<<(M_ROWS / 128) * (O_DIM / 128), 256, 0, stream>>>(Abuf, Wt, bias, out);
}

// Round 11
// 141.427 us; speedup vs baseline: 1.1616x; 1.1616x over previous
//
#include <hip/hip_runtime.h>
#include <hip/hip_bf16.h>

#define N_NODES 20000
#define BATCH   4
#define F_DIM   256
#define O_DIM   256
#define E_EDGES 160000
#define E_PAD   240000             // quad-padded CSR capacity (E + up to 3 per node)
#define M_ROWS  (BATCH * N_NODES)  // 80000
#define K_DIM   512                // concat: X (slices 0-7) | Xagg (slices 8-15)
// A layout: [16 slices][80000 rows][32 feats] bf16; row m = n*4 + b.
#define SLICE_A   2560000          // elems per A slice (80000*32)
#define SLICE_W   8192             // elems per Wt slice (256*32)

typedef __bf16 bf16_t;
typedef bf16_t bf16x8 __attribute__((ext_vector_type(8)));
typedef float  f32x4  __attribute__((ext_vector_type(4)));

// ---------- K1: sliced convert + weight transpose + deg zero + CSR-array zero ----------
__global__ void __launch_bounds__(256) k_prep(const float* __restrict__ X,
                                              const float* __restrict__ W1,
                                              const float* __restrict__ W2,
                                              bf16_t* __restrict__ A,
                                              bf16_t* __restrict__ Wt,
                                              int* __restrict__ deg,
                                              int* __restrict__ ccol,
                                              float* __restrict__ cval) {
    const int bid = blockIdx.x;
    const int tid = threadIdx.x;
    if (bid < 10000) {
        const int m = bid * 8 + (tid >> 5);      // m = n*4 + b
        const int n = m >> 2, b = m & 3;
        const int col = (tid & 31) * 8;          // feat octet
        const float* src = X + ((size_t)b * N_NODES + n) * F_DIM + col;
        const float4 v0 = *reinterpret_cast<const float4*>(src);
        const float4 v1 = *reinterpret_cast<const float4*>(src + 4);
        bf16x8 o = { (bf16_t)v0.x, (bf16_t)v0.y, (bf16_t)v0.z, (bf16_t)v0.w,
                     (bf16_t)v1.x, (bf16_t)v1.y, (bf16_t)v1.z, (bf16_t)v1.w };
        const int s = col >> 5;
        *reinterpret_cast<bf16x8*>(A + (size_t)s * SLICE_A + (size_t)m * 32 + (col & 31)) = o;
    } else if (bid < 10512) {
        const int k = bid - 10000;   // 0..511
        const float v = (k < F_DIM) ? W1[(size_t)k * O_DIM + tid]
                                    : W2[(size_t)(k - F_DIM) * O_DIM + tid];
        Wt[(size_t)(k >> 5) * SLICE_W + (size_t)tid * 32 + (k & 31)] = (bf16_t)v;
    } else if (bid < 10591) {
        const int idx = (bid - 10512) * 256 + tid;
        if (idx < N_NODES) deg[idx] = 0;
    } else {
        // zero padded CSR arrays (dummy edges: c=0, v=0)
        const int q = (bid - 10591) * 256 + tid;       // int4 index
        if (q < E_PAD / 4) {
            *reinterpret_cast<int4*>(ccol + q * 4) = (int4){0, 0, 0, 0};
            *reinterpret_cast<float4*>(cval + q * 4) = (float4){0.f, 0.f, 0.f, 0.f};
        }
    }
}

// ---------- CSR build ----------
__global__ void k_deg(const int* __restrict__ rows, int* __restrict__ deg) {
    int e = blockIdx.x * 256 + threadIdx.x;
    atomicAdd(&deg[rows[e]], 1);
}

// scan over QUAD-PADDED degrees: every node's range starts at a multiple of 4
__global__ void __launch_bounds__(1024) k_scan(const int* __restrict__ deg,
                                               int* __restrict__ offsets,
                                               int* __restrict__ cursor) {
    __shared__ int wsum[16];
    const int t = threadIdx.x;          // 0..1023
    const int lane = t & 63, wv = t >> 6;
    const int CH = 20;
    int b = t * CH; if (b > N_NODES) b = N_NODES;
    int e = b + CH; if (e > N_NODES) e = N_NODES;
    int s = 0;
    for (int i = b; i < e; ++i) s += (deg[i] + 3) & ~3;
    int ps = s;
#pragma unroll
    for (int off = 1; off < 64; off <<= 1) {
        int o = __shfl_up(ps, off);
        if (lane >= off) ps += o;
    }
    if (lane == 63) wsum[wv] = ps;
    __syncthreads();
    if (t == 0) {
        int run = 0;
#pragma unroll
        for (int j = 0; j < 16; ++j) { int v = wsum[j]; wsum[j] = run; run += v; }
        offsets[N_NODES] = run;         // == padded total
    }
    __syncthreads();
    int run = wsum[wv] + (ps - s);
    for (int i = b; i < e; ++i) {
        offsets[i] = run; cursor[i] = run;
        run += (deg[i] + 3) & ~3;
    }
}

__global__ void k_scatter(const int* __restrict__ rows, const int* __restrict__ cols,
                          const float* __restrict__ vals, int* __restrict__ cursor,
                          int* __restrict__ ccol, float* __restrict__ cval) {
    int e = blockIdx.x * 256 + threadIdx.x;
    int r = rows[e];
    int p = atomicAdd(&cursor[r], 1);
    ccol[p] = cols[e];
    cval[p] = vals[e];
}

// ---------- SpMM: sliced + XCD-pinned, group-per-node (r8 best), quad CSR ----------
// Block = slice x (blockIdx&7) x 16 nodes; group g (16 lanes) owns one node.
// Quad-padded CSR: beg 16B-aligned, all quads full -> ONE int4 + ONE float4
// index load per 4 edges (r10's scalar idx loads + joins were the regression),
// 4 gathers in flight, no remainder loop. Dummy edges (c=0,v=0) are no-ops.
__global__ void __launch_bounds__(256) k_spmm(const bf16_t* __restrict__ A,
                                              const int* __restrict__ offsets,
                                              const int* __restrict__ ccol,
                                              const float* __restrict__ cval,
                                              bf16_t* __restrict__ Aout) {
    const int x = blockIdx.x & 7;
    const int chunk = blockIdx.x >> 3;             // 0..1249
    const int g = threadIdx.x >> 4;                // 0..15: node group
    const int sub = threadIdx.x & 15;              // (batch sub>>2, feat-octet sub&3)
    const int n = chunk * 16 + g;
    const bf16_t* Xs = A + (size_t)x * SLICE_A + sub * 8;
    const int beg = offsets[n], end = offsets[n + 1];
    float acc[8] = {0.f,0.f,0.f,0.f,0.f,0.f,0.f,0.f};
    for (int i = beg; i < end; i += 4) {
        const int4   cc = *reinterpret_cast<const int4*>(ccol + i);
        const float4 vv = *reinterpret_cast<const float4*>(cval + i);
        bf16x8 x0 = *reinterpret_cast<const bf16x8*>(Xs + (size_t)cc.x * 128);
        bf16x8 x1 = *reinterpret_cast<const bf16x8*>(Xs + (size_t)cc.y * 128);
        bf16x8 x2 = *reinterpret_cast<const bf16x8*>(Xs + (size_t)cc.z * 128);
        bf16x8 x3 = *reinterpret_cast<const bf16x8*>(Xs + (size_t)cc.w * 128);
#pragma unroll
        for (int j = 0; j < 8; ++j)
            acc[j] += vv.x * (float)x0[j] + vv.y * (float)x1[j]
                    + vv.z * (float)x2[j] + vv.w * (float)x3[j];
    }
    bf16x8 o = { (bf16_t)acc[0], (bf16_t)acc[1], (bf16_t)acc[2], (bf16_t)acc[3],
                 (bf16_t)acc[4], (bf16_t)acc[5], (bf16_t)acc[6], (bf16_t)acc[7] };
    *reinterpret_cast<bf16x8*>(
        Aout + (size_t)(8 + x) * SLICE_A + (size_t)n * 128 + sub * 8) = o;
}

// ---------- GEMM: BK=64 sliced (r8 best) widened to 512 thr / 8 waves ----------
// Wave tile 64x32 (acc 4x2). LDS 64KB dbuf -> 2 blocks/CU = 16 waves/CU (was 8):
// doubles wave-level overlap across the vmcnt-drain barrier (the ~20% stall).
#define GLOAD_LDS16(gptr, lptr)                                                  \
    __builtin_amdgcn_global_load_lds(                                            \
        (const __attribute__((address_space(1))) unsigned int*)(gptr),           \
        (__attribute__((address_space(3))) unsigned int*)(lptr), 16, 0, 0)

__global__ void __launch_bounds__(512, 2) k_gemm(const bf16_t* __restrict__ A,   // sliced
                                                 const bf16_t* __restrict__ Bt,  // sliced Wt
                                                 const float* __restrict__ bias,
                                                 float* __restrict__ out) {      // [B*N][256]
    __shared__ bf16_t As[2 * 128 * 64];   // 32 KB
    __shared__ bf16_t Bs[2 * 128 * 64];   // 32 KB

    const int b0 = blockIdx.x;
    const int xcd = b0 & 7, idx = b0 >> 3;
    const int serial = (xcd < 2 ? xcd * 157 : 314 + (xcd - 2) * 156) + idx;
    const int tile_m = (serial >> 1) * 128;
    const int tile_n = (serial & 1) * 128;

    const int tid = threadIdx.x;
    const int lane = tid & 63;
    const int w = tid >> 6;               // 0..7
    const int wm = (w >> 2) * 64;         // 2 m-rows of waves
    const int wn = (w & 3) * 32;          // 4 n-cols of waves

    f32x4 acc[4][2];
#pragma unroll
    for (int i = 0; i < 4; ++i)
#pragma unroll
        for (int j = 0; j < 2; ++j) acc[i][j] = (f32x4){0.f, 0.f, 0.f, 0.f};

    // K-step t covers slices {2t, 2t+1}. LDS[row][j] = source chunk jj = j^(row&7);
    // chunk jj -> slice 2t+(jj>>2), in-slice offset row*32 + (jj&3)*8.
    auto STAGE = [&](int buf, int t) {
#pragma unroll
        for (int r = 0; r < 2; ++r) {
            const int c = r * 512 + tid;           // 0..1023
            const int row = c >> 3;
            const int jj = (c & 7) ^ (row & 7);
            const int s = t * 2 + (jj >> 2);
            GLOAD_LDS16(A  + (size_t)s * SLICE_A + (size_t)(tile_m + row) * 32 + (jj & 3) * 8,
                        &As[buf * 8192 + c * 8]);
            GLOAD_LDS16(Bt + (size_t)s * SLICE_W + (size_t)(tile_n + row) * 32 + (jj & 3) * 8,
                        &Bs[buf * 8192 + c * 8]);
        }
    };
    auto COMPUTE = [&](int buf) {
        const bf16_t* a  = &As[buf * 8192];
        const bf16_t* bb = &Bs[buf * 8192];
#pragma unroll
        for (int ks = 0; ks < 2; ++ks) {
            const int ch = ((((ks << 2) | (lane >> 4)) ^ (lane & 7)) << 3);
            bf16x8 af[4];
#pragma unroll
            for (int i = 0; i < 4; ++i)
                af[i] = *reinterpret_cast<const bf16x8*>(a + (wm + i * 16 + (lane & 15)) * 64 + ch);
#pragma unroll
            for (int j = 0; j < 2; ++j) {
                bf16x8 bfr = *reinterpret_cast<const bf16x8*>(bb + (wn + j * 16 + (lane & 15)) * 64 + ch);
#pragma unroll
                for (int i = 0; i < 4; ++i)
                    acc[i][j] = __builtin_amdgcn_mfma_f32_16x16x32_bf16(af[i], bfr, acc[i][j], 0, 0, 0);
            }
        }
    };

    STAGE(0, 0);
    __syncthreads();
#pragma unroll
    for (int t = 0; t < 8; t += 2) {
        STAGE(1, t + 1);
        COMPUTE(0);
        __syncthreads();
        if (t + 2 < 8) STAGE(0, t + 2);
        COMPUTE(1);
        __syncthreads();
    }

#pragma unroll
    for (int j = 0; j < 2; ++j) {
        const int col = tile_n + wn + j * 16 + (lane & 15);
        const float bv = bias[col];
#pragma unroll
        for (int i = 0; i < 4; ++i) {
            const int m0 = tile_m + wm + i * 16 + ((lane >> 4) << 2);
#pragma unroll
            for (int r = 0; r < 4; ++r) {
                const int m = m0 + r;                       // m = n*4 + b
                const size_t orow = (size_t)(m & 3) * N_NODES + (m >> 2);
                out[orow * O_DIM + col] = acc[i][j][r] + bv;
            }
        }
    }
}

extern "C" void kernel_launch(void* const* d_in, const int* in_sizes, int n_in,
                              void* d_out, int out_size, void* d_ws, size_t ws_size,
                              hipStream_t stream) {
    const float* X    = (const float*)d_in[0];
    const int*   rows = (const int*)d_in[1];
    const int*   cols = (const int*)d_in[2];
    const float* vals = (const float*)d_in[3];
    const float* W1   = (const float*)d_in[4];
    const float* W2   = (const float*)d_in[5];
    const float* bias = (const float*)d_in[6];
    float* out = (float*)d_out;

    char* ws = (char*)d_ws;
    size_t off = 0;
    bf16_t* Abuf = (bf16_t*)(ws + off); off += (size_t)16 * SLICE_A * 2;     // 81,920,000 B
    bf16_t* Wt   = (bf16_t*)(ws + off); off += (size_t)16 * SLICE_W * 2;     // 262,144 B
    int* deg     = (int*)(ws + off);    off += (size_t)N_NODES * 4;
    int* offsets = (int*)(ws + off);    off += (size_t)(N_NODES + 1) * 4;
    int* cursor  = (int*)(ws + off);    off += (size_t)N_NODES * 4;
    off = (off + 15) & ~(size_t)15;
    int*   ccol  = (int*)(ws + off);    off += (size_t)E_PAD * 4;
    float* cval  = (float*)(ws + off);  off += (size_t)E_PAD * 4;

    // prep grid: 10000 convert + 512 Wt + 79 deg-zero + 235 CSR-zero = 10826
    k_prep<<<10826, 256, 0, stream>>>(X, W1, W2, Abuf, Wt, deg, ccol, cval);
    k_deg<<<E_EDGES / 256, 256, 0, stream>>>(rows, deg);
    k_scan<<<1, 1024, 0, stream>>>(deg, offsets, cursor);
    k_scatter<<<E_EDGES / 256, 256, 0, stream>>>(rows, cols, vals, cursor, ccol, cval);
    k_spmm<<<10000, 256, 0, stream>>>(Abuf, offsets, ccol, cval, Abuf);
    k_gemm<<<(M_ROWS / 128) * (O_DIM / 128), 512, 0, stream>>>(Abuf, Wt, bias, out);
}